// Round 5
// baseline (147.827 us; speedup 1.0000x reference)
//
#include <hip/hip_runtime.h>

// KPConvInterSO3 via MFMA. N=16000, NB=32, A=4, K=15, CIN=COUT=32.
// Block = 256 threads = 4 waves; block handles 2 QUERIES; wave w owns anchor w.
// LDS ~18.4 KB -> 8 blocks/CU (32 waves = 100% occupancy cap) — R4 was
// latency-bound at 4 blocks/CU with nothing saturated.
// GEMM1 per (q,a): wf[k,c] = sum_b aw[b,k] x[b,c]; A-frag (weights) in registers.
// GEMM2 per a: out[q,d] = sum_{kc} wf[q,kc] W[kc,d]; W pre-permuted (prep_kernel).

typedef short bf16x8 __attribute__((ext_vector_type(8)));
typedef float f32x4  __attribute__((ext_vector_type(4)));

// round-half-up bf16: 2 VALU ops. <=1 ulp difference vs RNE on ties.
__device__ __forceinline__ unsigned short f2bf(float f) {
    unsigned u = __builtin_bit_cast(unsigned, f);
    return (unsigned short)((u + 0x8000u) >> 16);
}

// pack two floats -> (bf(hi)<<16)|bf(lo) in 3 VALU ops via v_perm_b32
__device__ __forceinline__ unsigned pack2bf(float hi, float lo) {
    unsigned uh = __builtin_bit_cast(unsigned, hi) + 0x8000u;
    unsigned ul = __builtin_bit_cast(unsigned, lo) + 0x8000u;
    return __builtin_amdgcn_perm(uh, ul, 0x07060302u);
}

// Wp[kk][d][e] = bf16(W[k][c][d]), kcs = kk*32+e = c*16+k (k=15 -> 0 pad).
__global__ void prep_kernel(const float* __restrict__ W, unsigned short* __restrict__ Wp) {
    const int idx = blockIdx.x * 256 + threadIdx.x;   // 0..16383
    const int kk = idx >> 10, d = (idx >> 5) & 31, e = idx & 31;
    const int kcs = kk * 32 + e;
    const int c = kcs >> 4, k = kcs & 15;
    const float v = (k < 15) ? W[(k * 32 + c) * 32 + d] : 0.0f;
    Wp[idx] = f2bf(v);
}

__global__ __launch_bounds__(256) void kpconv_mfma(
    const float* __restrict__ q_pts,    // [N,3]
    const float* __restrict__ s_pts,    // [M,3]
    const int*   __restrict__ inds,     // [N,32]
    const float* __restrict__ x,        // [M,4,32]
    const float* __restrict__ kp,       // [15,3]
    const float* __restrict__ anchors,  // [4,3,3]
    const unsigned short* __restrict__ Wp, // [16][32][32] bf16 (permuted)
    float*       __restrict__ out)      // [N,4,32]
{
    // xa_s: [a][q][c][b_phys] bf16, 16KB; per-a 4KB slice later aliased
    // (wave-private, in-order DS) by wf[q] at q*512 + (kcs ^ (q*16)).
    __shared__ __align__(16) unsigned short xa_s[8192];
    // nbr: [q][b] float4, padded: float4 idx = q*36 + b + (b>>3)
    __shared__ __align__(16) float nbr[288];
    __shared__ __align__(16) float rk_s[256];   // [a][k] float4; k=15 -> (0,0,0,1e30)
    __shared__ int sidx[64];                    // [q][b]

    const int t  = threadIdx.x;
    const int n0 = blockIdx.x * 2;

    // ---------------- P0: neighbors + rotated kernel points ----------------
    if (t < 64) {
        const int q = t >> 5, b = t & 31;
        const int idx = inds[(n0 + q) * 32 + b];
        sidx[t] = idx;
        const float qx = q_pts[(n0 + q) * 3 + 0];
        const float qy = q_pts[(n0 + q) * 3 + 1];
        const float qz = q_pts[(n0 + q) * 3 + 2];
        const float nx = s_pts[idx * 3 + 0] - qx;
        const float ny = s_pts[idx * 3 + 1] - qy;
        const float nz = s_pts[idx * 3 + 2] - qz;
        float4 v; v.x = nx; v.y = ny; v.z = nz; v.w = nx*nx + ny*ny + nz*nz;
        *(float4*)&nbr[(q * 36 + b + (b >> 3)) * 4] = v;
    } else if (t < 128) {
        const int j = t - 64;
        const int a = j >> 4, k = j & 15;
        float4 v;
        if (k < 15) {
            const float kx = kp[k*3+0], ky = kp[k*3+1], kz = kp[k*3+2];
            const float* R = anchors + a * 9;
            v.x = R[0]*kx + R[1]*ky + R[2]*kz;
            v.y = R[3]*kx + R[4]*ky + R[5]*kz;
            v.z = R[6]*kx + R[7]*ky + R[8]*kz;
            v.w = v.x*v.x + v.y*v.y + v.z*v.z;
        } else {
            v.x = 0.0f; v.y = 0.0f; v.z = 0.0f; v.w = 1e30f;  // kills k=15 row
        }
        *(float4*)&rk_s[(a * 16 + k) * 4] = v;
    }
    __syncthreads();

    // ---------------- P2: gather x -> xa_s[a][q][c][b'] (bf16, transposed) ----------------
    // t -> ah = t>>7 (anchor pair), q = (t>>6)&1, bg = (t>>3)&7, c4 = t&7.
    // b-block swizzle: b' = (b&7) | (((b>>3) ^ (c>>2 & 3)) << 3).
    {
        const int c4 = t & 7, bg = (t >> 3) & 7, q = (t >> 6) & 1, ah = t >> 7;
        #pragma unroll
        for (int aa = 0; aa < 2; ++aa) {
            const int a = ah * 2 + aa;
            float4 v[4];
            #pragma unroll
            for (int i = 0; i < 4; ++i) {
                const int row = sidx[q * 32 + 4 * bg + i];
                v[i] = ((const float4*)x)[row * 32 + a * 8 + c4];
            }
            const float* vp = (const float*)v;
            #pragma unroll
            for (int j = 0; j < 4; ++j) {
                const int c  = 4 * c4 + j;
                const int fc = c4 & 3;                      // (c>>2)&3
                const int bb = 4 * (bg & 1) + 8 * ((bg >> 1) ^ fc);
                uint2 w;
                w.x = pack2bf(vp[1 * 4 + j], vp[0 * 4 + j]);
                w.y = pack2bf(vp[3 * 4 + j], vp[2 * 4 + j]);
                *(uint2*)&xa_s[((a * 2 + q) * 32 + c) * 32 + bb] = w;
            }
        }
    }
    __syncthreads();

    // ---------------- Per-wave: anchor a = wave id ----------------
    const int a    = t >> 6;
    const int lane = t & 63;
    const int l15  = lane & 15;
    const int quad = lane >> 4;
    const int fc   = (l15 >> 2) & 3;

    const float4 r4 = *(const float4*)&rk_s[(a * 16 + l15) * 4];
    unsigned short* wfb = &xa_s[a * 2048];

    // GEMM1: per q, wf[k,c] = sum_b aw[b,k]*x[b,c].
    // A-frag in registers: lane (k=l15, b=quad*8+j) computes weight(q,a,b,k).
    #pragma unroll
    for (int q = 0; q < 2; ++q) {
        float w8[8];
        #pragma unroll
        for (int j = 0; j < 8; ++j) {
            const int b = quad * 8 + j;
            const float4 nb = *(const float4*)&nbr[(q * 36 + b + (b >> 3)) * 4];
            const float dot = fmaf(nb.x, r4.x, fmaf(nb.y, r4.y, nb.z * r4.z));
            const float sq  = fmaf(-2.0f, dot, nb.w + r4.w);
            const float d   = sqrtf(fmaxf(sq, 1e-12f));
            w8[j] = fmaxf(fmaf(d, -(1.0f / 0.6f), 1.0f), 0.0f);
        }
        uint4 uu;
        uu.x = pack2bf(w8[1], w8[0]); uu.y = pack2bf(w8[3], w8[2]);
        uu.z = pack2bf(w8[5], w8[4]); uu.w = pack2bf(w8[7], w8[6]);
        const bf16x8 afr = __builtin_bit_cast(bf16x8, uu);

        const bf16x8 b0 = *(const bf16x8*)&xa_s[((a*2 + q)*32 + l15)      * 32 + 8 * (quad ^ fc)];
        const bf16x8 b1 = *(const bf16x8*)&xa_s[((a*2 + q)*32 + l15 + 16) * 32 + 8 * (quad ^ fc)];
        f32x4 d0 = {0.f,0.f,0.f,0.f}, d1 = {0.f,0.f,0.f,0.f};
        d0 = __builtin_amdgcn_mfma_f32_16x16x32_bf16(afr, b0, d0, 0, 0, 0);
        d1 = __builtin_amdgcn_mfma_f32_16x16x32_bf16(afr, b1, d1, 0, 0, 0);
        // D: col c = l15 (+16), rows k = quad*4+reg. Store at q*512 + (kcs^(q*16)).
        uint2 s0, s1;
        s0.x = pack2bf(d0[1], d0[0]); s0.y = pack2bf(d0[3], d0[2]);
        s1.x = pack2bf(d1[1], d1[0]); s1.y = pack2bf(d1[3], d1[2]);
        *(uint2*)&wfb[q*512 + (( l15       * 16 + quad * 4) ^ (q * 16))] = s0;
        *(uint2*)&wfb[q*512 + (((l15 + 16) * 16 + quad * 4) ^ (q * 16))] = s1;
    }
    // no barrier: xa_s[a] is wave-private after the P2 barrier; DS in-order per wave

    // GEMM2: out[q,d] = sum_{kc} wf[q,kc] * W[kc,d]; A rows m -> q = m&1
    const int qq = l15 & 1;
    f32x4 o0 = {0.f,0.f,0.f,0.f}, o1 = {0.f,0.f,0.f,0.f};
    #pragma unroll
    for (int kk = 0; kk < 16; ++kk) {
        const bf16x8 a2 = *(const bf16x8*)&wfb[qq*512 + ((kk*32 + quad*8) ^ (qq*16))];
        const bf16x8 w0 = *(const bf16x8*)&Wp[kk*1024 + l15*32 + quad*8];
        const bf16x8 w1 = *(const bf16x8*)&Wp[kk*1024 + (l15+16)*32 + quad*8];
        o0 = __builtin_amdgcn_mfma_f32_16x16x32_bf16(a2, w0, o0, 0, 0, 0);
        o1 = __builtin_amdgcn_mfma_f32_16x16x32_bf16(a2, w1, o1, 0, 0, 0);
    }
    // D: col d = l15 (+16), rows = quad*4+reg; rows 0,1 = q0,q1 (rows 2,3 dup)
    if (quad == 0) {
        #pragma unroll
        for (int r = 0; r < 2; ++r) {
            out[((n0 + r) * 4 + a) * 32 + l15]      = o0[r];
            out[((n0 + r) * 4 + a) * 32 + 16 + l15] = o1[r];
        }
    }
}

extern "C" void kernel_launch(void* const* d_in, const int* in_sizes, int n_in,
                              void* d_out, int out_size, void* d_ws, size_t ws_size,
                              hipStream_t stream) {
    const float* q_pts   = (const float*)d_in[0];
    const float* s_pts   = (const float*)d_in[1];
    const int*   inds    = (const int*)d_in[2];
    const float* x       = (const float*)d_in[3];
    const float* kp      = (const float*)d_in[4];
    const float* anchors = (const float*)d_in[5];
    const float* weights = (const float*)d_in[6];
    float*       out     = (float*)d_out;
    unsigned short* Wp   = (unsigned short*)d_ws;   // 32 KB

    prep_kernel<<<dim3(64), dim3(256), 0, stream>>>(weights, Wp);
    kpconv_mfma<<<dim3(8000), dim3(256), 0, stream>>>(
        q_pts, s_pts, inds, x, kp, anchors, Wp, out);
}

// Round 6
// 123.834 us; speedup vs baseline: 1.1938x; 1.1938x over previous
//
#include <hip/hip_runtime.h>

// KPConvInterSO3 via MFMA. N=16000, NB=32, A=4, K=15, CIN=COUT=32.
// Block = 256 threads = 4 waves; block handles 4 queries; wave w owns anchor w.
// R5 lesson: throughput-per-total-work is constant -> cut work, not occupancy.
// R6: x pre-converted to bf16 (4 MB, fits each XCD's L2) by prep_x; gather
// reads bf16 (half bytes, L2-hit latency), repack via v_perm; inds loaded
// directly (no sidx LDS, single barrier).

typedef short bf16x8 __attribute__((ext_vector_type(8)));
typedef float f32x4  __attribute__((ext_vector_type(4)));

// round-half-up bf16: 2 VALU ops. <=1 ulp difference vs RNE on ties.
__device__ __forceinline__ unsigned short f2bf(float f) {
    unsigned u = __builtin_bit_cast(unsigned, f);
    return (unsigned short)((u + 0x8000u) >> 16);
}

// pack two floats -> (bf(hi)<<16)|bf(lo) in 3 VALU ops via v_perm_b32
__device__ __forceinline__ unsigned pack2bf(float hi, float lo) {
    unsigned uh = __builtin_bit_cast(unsigned, hi) + 0x8000u;
    unsigned ul = __builtin_bit_cast(unsigned, lo) + 0x8000u;
    return __builtin_amdgcn_perm(uh, ul, 0x07060302u);
}

// Wp[kk][d][e] = bf16(W[k][c][d]), kcs = kk*32+e = c*16+k (k=15 -> 0 pad).
__global__ void prep_w(const float* __restrict__ W, unsigned short* __restrict__ Wp) {
    const int idx = blockIdx.x * 256 + threadIdx.x;   // 0..16383
    const int kk = idx >> 10, d = (idx >> 5) & 31, e = idx & 31;
    const int kcs = kk * 32 + e;
    const int c = kcs >> 4, k = kcs & 15;
    const float v = (k < 15) ? W[(k * 32 + c) * 32 + d] : 0.0f;
    Wp[idx] = f2bf(v);
}

// x (fp32, 2,048,000 floats) -> xb (bf16). 1000 blocks x 256 thr x 8 floats.
__global__ void prep_x(const float* __restrict__ x, unsigned short* __restrict__ xb) {
    const int i = (blockIdx.x * 256 + threadIdx.x) * 8;
    const float4 v0 = *(const float4*)&x[i];
    const float4 v1 = *(const float4*)&x[i + 4];
    uint4 u;
    u.x = pack2bf(v0.y, v0.x); u.y = pack2bf(v0.w, v0.z);
    u.z = pack2bf(v1.y, v1.x); u.w = pack2bf(v1.w, v1.z);
    *(uint4*)&xb[i] = u;
}

__global__ __launch_bounds__(256) void kpconv_mfma(
    const float* __restrict__ q_pts,    // [N,3]
    const float* __restrict__ s_pts,    // [M,3]
    const int*   __restrict__ inds,     // [N,32]
    const unsigned short* __restrict__ xb, // [M,4,32] bf16
    const float* __restrict__ kp,       // [15,3]
    const float* __restrict__ anchors,  // [4,3,3]
    const unsigned short* __restrict__ Wp, // [16][32][32] bf16 (permuted)
    float*       __restrict__ out)      // [N,4,32]
{
    // xa_s: [a][q][c][b_phys] bf16, 32KB; per-a 4KB slice later aliased
    // (wave-private, in-order DS) by wf[q] at q*512 + (kcs ^ (q*16)).
    __shared__ __align__(16) unsigned short xa_s[16384];
    // nbr: [q][b] float4, padded: float4 idx = q*36 + b + (b>>3)
    __shared__ __align__(16) float nbr[576];
    __shared__ __align__(16) float rk_s[256];   // [a][k] float4; k=15 -> (0,0,0,1e30)

    const int t  = threadIdx.x;
    const int n0 = blockIdx.x * 4;

    // ---------------- P2: gather xb -> xa_s[a][q][c][b'] (register transpose) ----
    // t -> (q = t>>6, bg = (t>>3)&7, c4 = t&7). Loads issue immediately (no
    // dependence on any LDS). b-block swizzle: b' = (b&7)|(((b>>3)^(c>>2&3))<<3).
    {
        const int c4 = t & 7, bg = (t >> 3) & 7, q = t >> 6;
        const int4 rows = *(const int4*)&inds[(n0 + q) * 32 + 4 * bg];
        const int fc  = c4 & 3;
        const int bb  = 4 * (bg & 1);
        const int blk = 8 * ((bg >> 1) ^ fc);
        unsigned short* base = &xa_s[(q * 32) * 32 + blk + bb];
        #pragma unroll
        for (int a = 0; a < 4; ++a) {
            const uint2 r0 = *(const uint2*)&xb[rows.x * 128 + a * 32 + c4 * 4];
            const uint2 r1 = *(const uint2*)&xb[rows.y * 128 + a * 32 + c4 * 4];
            const uint2 r2 = *(const uint2*)&xb[rows.z * 128 + a * 32 + c4 * 4];
            const uint2 r3 = *(const uint2*)&xb[rows.w * 128 + a * 32 + c4 * 4];
            unsigned short* pa = base + a * 4096;
            uint2 w;
            w.x = __builtin_amdgcn_perm(r1.x, r0.x, 0x05040100u);
            w.y = __builtin_amdgcn_perm(r3.x, r2.x, 0x05040100u);
            *(uint2*)&pa[(4 * c4 + 0) * 32] = w;
            w.x = __builtin_amdgcn_perm(r1.x, r0.x, 0x07060302u);
            w.y = __builtin_amdgcn_perm(r3.x, r2.x, 0x07060302u);
            *(uint2*)&pa[(4 * c4 + 1) * 32] = w;
            w.x = __builtin_amdgcn_perm(r1.y, r0.y, 0x05040100u);
            w.y = __builtin_amdgcn_perm(r3.y, r2.y, 0x05040100u);
            *(uint2*)&pa[(4 * c4 + 2) * 32] = w;
            w.x = __builtin_amdgcn_perm(r1.y, r0.y, 0x07060302u);
            w.y = __builtin_amdgcn_perm(r3.y, r2.y, 0x07060302u);
            *(uint2*)&pa[(4 * c4 + 3) * 32] = w;
        }
    }

    // ---------------- P0: neighbors + rotated kernel points ----------------
    if (t < 128) {
        const int q = t >> 5, b = t & 31;
        const int idx = inds[(n0 + q) * 32 + b];
        const float qx = q_pts[(n0 + q) * 3 + 0];
        const float qy = q_pts[(n0 + q) * 3 + 1];
        const float qz = q_pts[(n0 + q) * 3 + 2];
        const float nx = s_pts[idx * 3 + 0] - qx;
        const float ny = s_pts[idx * 3 + 1] - qy;
        const float nz = s_pts[idx * 3 + 2] - qz;
        float4 v; v.x = nx; v.y = ny; v.z = nz; v.w = nx*nx + ny*ny + nz*nz;
        *(float4*)&nbr[(q * 36 + b + (b >> 3)) * 4] = v;
    } else if (t < 192) {
        const int j = t - 128;
        const int a = j >> 4, k = j & 15;
        float4 v;
        if (k < 15) {
            const float kx = kp[k*3+0], ky = kp[k*3+1], kz = kp[k*3+2];
            const float* R = anchors + a * 9;
            v.x = R[0]*kx + R[1]*ky + R[2]*kz;
            v.y = R[3]*kx + R[4]*ky + R[5]*kz;
            v.z = R[6]*kx + R[7]*ky + R[8]*kz;
            v.w = v.x*v.x + v.y*v.y + v.z*v.z;
        } else {
            v.x = 0.0f; v.y = 0.0f; v.z = 0.0f; v.w = 1e30f;  // kills k=15 row
        }
        *(float4*)&rk_s[(a * 16 + k) * 4] = v;
    }
    __syncthreads();   // single barrier: xa_s + nbr + rk_s all visible

    // ---------------- Per-wave: anchor a = wave id ----------------
    const int a    = t >> 6;
    const int lane = t & 63;
    const int l15  = lane & 15;
    const int quad = lane >> 4;
    const int fc   = (l15 >> 2) & 3;

    const float4 r4 = *(const float4*)&rk_s[(a * 16 + l15) * 4];
    unsigned short* wfb = &xa_s[a * 4096];

    // GEMM1: per q, wf[k,c] = sum_b aw[b,k]*x[b,c].
    // A-frag in registers: lane (k=l15, b=quad*8+j) computes weight(q,a,b,k).
    #pragma unroll
    for (int q = 0; q < 4; ++q) {
        float w8[8];
        #pragma unroll
        for (int j = 0; j < 8; ++j) {
            const int b = quad * 8 + j;
            const float4 nb = *(const float4*)&nbr[(q * 36 + b + (b >> 3)) * 4];
            const float dot = fmaf(nb.x, r4.x, fmaf(nb.y, r4.y, nb.z * r4.z));
            const float sq  = fmaf(-2.0f, dot, nb.w + r4.w);
            const float d   = sqrtf(fmaxf(sq, 1e-12f));
            w8[j] = fmaxf(fmaf(d, -(1.0f / 0.6f), 1.0f), 0.0f);
        }
        uint4 uu;
        uu.x = pack2bf(w8[1], w8[0]); uu.y = pack2bf(w8[3], w8[2]);
        uu.z = pack2bf(w8[5], w8[4]); uu.w = pack2bf(w8[7], w8[6]);
        const bf16x8 afr = __builtin_bit_cast(bf16x8, uu);

        const bf16x8 b0 = *(const bf16x8*)&xa_s[((a*4 + q)*32 + l15)      * 32 + 8 * (quad ^ fc)];
        const bf16x8 b1 = *(const bf16x8*)&xa_s[((a*4 + q)*32 + l15 + 16) * 32 + 8 * (quad ^ fc)];
        f32x4 d0 = {0.f,0.f,0.f,0.f}, d1 = {0.f,0.f,0.f,0.f};
        d0 = __builtin_amdgcn_mfma_f32_16x16x32_bf16(afr, b0, d0, 0, 0, 0);
        d1 = __builtin_amdgcn_mfma_f32_16x16x32_bf16(afr, b1, d1, 0, 0, 0);
        // D: col c = l15 (+16), rows k = quad*4+reg. Store at q*512 + (kcs^(q*16)).
        uint2 s0, s1;
        s0.x = pack2bf(d0[1], d0[0]); s0.y = pack2bf(d0[3], d0[2]);
        s1.x = pack2bf(d1[1], d1[0]); s1.y = pack2bf(d1[3], d1[2]);
        *(uint2*)&wfb[q*512 + (( l15       * 16 + quad * 4) ^ (q * 16))] = s0;
        *(uint2*)&wfb[q*512 + (((l15 + 16) * 16 + quad * 4) ^ (q * 16))] = s1;
    }
    // no barrier: xa_s[a] is wave-private after the single barrier; DS in-order

    // GEMM2: out[q,d] = sum_{kc} wf[q,kc] * W[kc,d]; A rows m -> q = m&3
    const int qq = l15 & 3;
    f32x4 o0 = {0.f,0.f,0.f,0.f}, o1 = {0.f,0.f,0.f,0.f};
    #pragma unroll
    for (int kk = 0; kk < 16; ++kk) {
        const bf16x8 a2 = *(const bf16x8*)&wfb[qq*512 + ((kk*32 + quad*8) ^ (qq*16))];
        const bf16x8 w0 = *(const bf16x8*)&Wp[kk*1024 + l15*32 + quad*8];
        const bf16x8 w1 = *(const bf16x8*)&Wp[kk*1024 + (l15+16)*32 + quad*8];
        o0 = __builtin_amdgcn_mfma_f32_16x16x32_bf16(a2, w0, o0, 0, 0, 0);
        o1 = __builtin_amdgcn_mfma_f32_16x16x32_bf16(a2, w1, o1, 0, 0, 0);
    }
    // D: col d = l15 (+16), rows = quad*4+reg; quad 0 rows 0..3 = q
    if (quad == 0) {
        #pragma unroll
        for (int r = 0; r < 4; ++r) {
            out[((n0 + r) * 4 + a) * 32 + l15]      = o0[r];
            out[((n0 + r) * 4 + a) * 32 + 16 + l15] = o1[r];
        }
    }
}

extern "C" void kernel_launch(void* const* d_in, const int* in_sizes, int n_in,
                              void* d_out, int out_size, void* d_ws, size_t ws_size,
                              hipStream_t stream) {
    const float* q_pts   = (const float*)d_in[0];
    const float* s_pts   = (const float*)d_in[1];
    const int*   inds    = (const int*)d_in[2];
    const float* x       = (const float*)d_in[3];
    const float* kp      = (const float*)d_in[4];
    const float* anchors = (const float*)d_in[5];
    const float* weights = (const float*)d_in[6];
    float*       out     = (float*)d_out;

    unsigned short* Wp = (unsigned short*)d_ws;                       // 32 KB
    unsigned short* xb = (unsigned short*)((char*)d_ws + (1 << 16));  // 4 MB

    prep_w<<<dim3(64),   dim3(256), 0, stream>>>(weights, Wp);
    prep_x<<<dim3(1000), dim3(256), 0, stream>>>(x, xb);
    kpconv_mfma<<<dim3(4000), dim3(256), 0, stream>>>(
        q_pts, s_pts, inds, xb, kp, anchors, Wp, out);
}